// Round 10
// baseline (684.037 us; speedup 1.0000x reference)
//
#include <hip/hip_runtime.h>
#include <hip/hip_bf16.h>
#include <hip/hip_cooperative_groups.h>

namespace cg = cooperative_groups;

// ---------------------------------------------------------------------------
// SoftBlobGIN round 10: whole GIN layer fused into one cooperative kernel
// (t1/t2 live in registers across grid.sync; BN stats via atomics).
// Saves ~102 MB intermediate traffic per layer vs R9.
// ---------------------------------------------------------------------------

#define HH 128
typedef unsigned short u16;
typedef unsigned int u32;
typedef __attribute__((ext_vector_type(8))) short bf16x8;
typedef __attribute__((ext_vector_type(4))) float f32x4;

__device__ __forceinline__ void atomAddF(float* p, float v) { unsafeAtomicAdd(p, v); }

__device__ __forceinline__ u16 f2bf(float f) {          // RNE f32->bf16
    u32 u = __float_as_uint(f);
    u += 0x7fffu + ((u >> 16) & 1u);
    return (u16)(u >> 16);
}
__device__ __forceinline__ float bf2f_lo(u32 u) { return __uint_as_float(u << 16); }
__device__ __forceinline__ float bf2f_hi(u32 u) { return __uint_as_float(u & 0xffff0000u); }
__device__ __forceinline__ void split2(float v, u16& hi, u16& lo) {
    u16 h_ = f2bf(v);
    float hf = __uint_as_float(((u32)h_) << 16);
    hi = h_;
    lo = f2bf(v - hf);
}
__device__ __forceinline__ u32 swz(u32 row, u32 kByte, u32 strideB) {
    return (row * strideB + kByte) ^ ((row & 7u) << 4);
}

#define WTOT (8192 + 6 * 16384)

// ---------------- weight prep ----------------
__global__ void k_prep(const float* __restrict__ inp_w, const float* __restrict__ m1,
                       const float* __restrict__ m2, u16* __restrict__ Whi,
                       u16* __restrict__ Wlo) {
    int b = blockIdx.x;  // 0..6
    int t = threadIdx.x; // 256
    if (b == 0) {
        for (int idx = t; idx < 128 * 64; idx += 256) {
            int c = idx >> 6, k = idx & 63;
            u16 hi, lo;
            split2(inp_w[k * 128 + c], hi, lo);
            Whi[idx] = hi; Wlo[idx] = lo;
        }
    } else {
        const float* W = (b <= 3) ? m1 + (size_t)(b - 1) * 16384
                                  : m2 + (size_t)(b - 4) * 16384;
        u16* dh = Whi + 8192 + (size_t)(b - 1) * 16384;
        u16* dl = Wlo + 8192 + (size_t)(b - 1) * 16384;
        for (int idx = t; idx < 16384; idx += 256) {
            int c = idx >> 7, k = idx & 127;
            u16 hi, lo;
            split2(W[k * 128 + c], hi, lo);
            dh[idx] = hi; dl[idx] = lo;
        }
    }
}

// ---------------- x pre-split ----------------
__global__ void k_split(const float* __restrict__ x, u16* __restrict__ xhi,
                        u16* __restrict__ xlo, int total4) {
    int i = blockIdx.x * 256 + threadIdx.x;
    if (i >= total4) return;
    float4 v = *(const float4*)(x + (size_t)i * 4);
    u16 h0, h1, h2, h3, l0, l1, l2, l3;
    split2(v.x, h0, l0); split2(v.y, h1, l1);
    split2(v.z, h2, l2); split2(v.w, h3, l3);
    uint2 ph = {(u32)h0 | ((u32)h1 << 16), (u32)h2 | ((u32)h3 << 16)};
    uint2 pl = {(u32)l0 | ((u32)l1 << 16), (u32)l2 | ((u32)l3 << 16)};
    *(uint2*)(xhi + (size_t)i * 4) = ph;
    *(uint2*)(xlo + (size_t)i * 4) = pl;
}

// ---------------- CSR build (4 edges/thread) ----------------
__global__ void k_hist(const int* __restrict__ ei, int* __restrict__ deg, int E) {
    int i4 = blockIdx.x * 256 + threadIdx.x;
    int e0 = i4 * 4;
    if (e0 + 3 < E) {
        int4 d = *(const int4*)(ei + E + e0);
        atomicAdd(&deg[d.x], 1);
        atomicAdd(&deg[d.y], 1);
        atomicAdd(&deg[d.z], 1);
        atomicAdd(&deg[d.w], 1);
    } else {
        for (int e = e0; e < E; e++) atomicAdd(&deg[ei[E + e]], 1);
    }
}

__global__ void k_bsum(const int* __restrict__ deg, int* __restrict__ bsum, int N) {
    int t = threadIdx.x;
    int i = blockIdx.x * 256 + t;
    int v = (i < N) ? deg[i] : 0;
    for (int o = 32; o; o >>= 1) v += __shfl_down(v, o);
    __shared__ int ws_[4];
    if ((t & 63) == 0) ws_[t >> 6] = v;
    __syncthreads();
    if (t == 0) bsum[blockIdx.x] = ws_[0] + ws_[1] + ws_[2] + ws_[3];
}

__global__ void k_scan1(const int* __restrict__ bsum, int* __restrict__ boff,
                        int* __restrict__ rowptrN, int nch) {
    int t = threadIdx.x;  // 256
    int v = (t < nch) ? bsum[t] : 0;
    int l = t & 63, w = t >> 6;
    int sv = v;
    for (int o = 1; o < 64; o <<= 1) { int u = __shfl_up(sv, o); if (l >= o) sv += u; }
    __shared__ int wsum[4];
    if (l == 63) wsum[w] = sv;
    __syncthreads();
    int add = 0;
    for (int j = 0; j < w; j++) add += wsum[j];
    if (t < nch) boff[t] = sv - v + add;
    if (t == nch - 1) *rowptrN = sv + add;
}

__global__ void k_scan2(const int* __restrict__ deg, const int* __restrict__ boff,
                        int* __restrict__ rowptr, int* __restrict__ cursor, int N) {
    int b = blockIdx.x, t = threadIdx.x, i = b * 256 + t;
    int v = (i < N) ? deg[i] : 0;
    int l = t & 63, w = t >> 6;
    int sv = v;
    for (int o = 1; o < 64; o <<= 1) { int u = __shfl_up(sv, o); if (l >= o) sv += u; }
    __shared__ int wsum[4];
    if (l == 63) wsum[w] = sv;
    __syncthreads();
    int add = boff[b];
    for (int j = 0; j < w; j++) add += wsum[j];
    if (i < N) { int e = sv - v + add; rowptr[i] = e; cursor[i] = e; }
}

__global__ void k_fill(const int* __restrict__ ei, int* __restrict__ cursor,
                       int* __restrict__ col, int E) {
    int i4 = blockIdx.x * 256 + threadIdx.x;
    int e0 = i4 * 4;
    if (e0 + 3 < E) {
        int4 s = *(const int4*)(ei + e0);
        int4 d = *(const int4*)(ei + E + e0);
        int p0 = atomicAdd(&cursor[d.x], 1);
        int p1 = atomicAdd(&cursor[d.y], 1);
        int p2 = atomicAdd(&cursor[d.z], 1);
        int p3 = atomicAdd(&cursor[d.w], 1);
        col[p0] = s.x;
        col[p1] = s.y;
        col[p2] = s.z;
        col[p3] = s.w;
    } else {
        for (int e = e0; e < E; e++) {
            int pos = atomicAdd(&cursor[ei[E + e]], 1);
            col[pos] = ei[e];
        }
    }
}

// ---------------- input GEMM: [N,64] hi/lo @ [64,128] -> bf16 hb ------------
__global__ __launch_bounds__(512) void k_ingemm(
    const u16* __restrict__ xhi, const u16* __restrict__ xlo,
    const u16* __restrict__ Whi, const u16* __restrict__ Wlo,
    const float* __restrict__ bias, u16* __restrict__ outb,
    int Nrows, int ntiles) {
    constexpr int KD = 64;
    constexpr u32 STR = 128;
    __shared__ u16 s_A[2][128 * KD];
    __shared__ u16 s_B[2][128 * KD];
    const int t = threadIdx.x;
    constexpr int KCB = KD / 8;              // 8 uint4 chunks/row
    constexpr int NAU = 128 * KCB / 512;     // 2

    // stage B once
#pragma unroll
    for (int i = 0; i < NAU; i++) {
        int idx = i * 512 + t;
        int c = idx / KCB, kc = idx % KCB;
        u32 off = swz(c, kc * 16, STR);
        *(uint4*)((char*)s_B[0] + off) = *(const uint4*)(Whi + (size_t)c * KD + kc * 8);
        *(uint4*)((char*)s_B[1] + off) = *(const uint4*)(Wlo + (size_t)c * KD + kc * 8);
    }

    const int l = t & 63, w = t >> 6;
    const int c0 = l & 15;
    const u32 kOffB = (u32)(l >> 4) * 16u;
    const u32 rA_row = w * 16 + c0;

    for (int tile = blockIdx.x; tile < ntiles; tile += gridDim.x) {
#pragma unroll
        for (int i = 0; i < NAU; i++) {
            int idx = i * 512 + t;
            int r = idx / KCB, kc = idx % KCB;
            int gr = tile * 128 + r;
            uint4 vh = {0, 0, 0, 0}, vl = {0, 0, 0, 0};
            if (gr < Nrows) {
                vh = *(const uint4*)(xhi + (size_t)gr * KD + kc * 8);
                vl = *(const uint4*)(xlo + (size_t)gr * KD + kc * 8);
            }
            u32 off = swz(r, kc * 16, STR);
            *(uint4*)((char*)s_A[0] + off) = vh;
            *(uint4*)((char*)s_A[1] + off) = vl;
        }
        __syncthreads();
        f32x4 acc[8];
#pragma unroll
        for (int n = 0; n < 8; n++) acc[n] = (f32x4){0.f, 0.f, 0.f, 0.f};
#pragma unroll
        for (int kk = 0; kk < KD / 32; kk++) {
            u32 kb = kk * 64 + kOffB;
            bf16x8 ah = *(const bf16x8*)((char*)s_A[0] + swz(rA_row, kb, STR));
            bf16x8 al = *(const bf16x8*)((char*)s_A[1] + swz(rA_row, kb, STR));
#pragma unroll
            for (int n = 0; n < 8; n++) {
                u32 ob = swz(n * 16 + c0, kb, STR);
                bf16x8 bh = *(const bf16x8*)((char*)s_B[0] + ob);
                bf16x8 bl = *(const bf16x8*)((char*)s_B[1] + ob);
                acc[n] = __builtin_amdgcn_mfma_f32_16x16x32_bf16(ah, bh, acc[n], 0, 0, 0);
                acc[n] = __builtin_amdgcn_mfma_f32_16x16x32_bf16(al, bh, acc[n], 0, 0, 0);
                acc[n] = __builtin_amdgcn_mfma_f32_16x16x32_bf16(ah, bl, acc[n], 0, 0, 0);
            }
        }
        const int rbase = tile * 128 + w * 16 + ((l >> 4) << 2);
#pragma unroll
        for (int n = 0; n < 8; n++) {
            const int colc = n * 16 + c0;
            const float bv = bias[colc];
#pragma unroll
            for (int j = 0; j < 4; j++) {
                int gr = rbase + j;
                if (gr < Nrows) outb[(size_t)gr * HH + colc] = f2bf(acc[n][j] + bv);
            }
        }
        __syncthreads();
    }
}

// ---------------- fused GIN layer (cooperative): z -> h, t1/t2 in regs ------
__global__ __launch_bounds__(512, 1) void k_layer(
    const u16* __restrict__ zhi, const u16* __restrict__ zlo,
    const u16* __restrict__ W1hi, const u16* __restrict__ W1lo,
    const float* __restrict__ b1, const float* __restrict__ g1,
    const float* __restrict__ be1,
    const u16* __restrict__ W2hi, const u16* __restrict__ W2lo,
    const float* __restrict__ b2, const float* __restrict__ g2,
    const float* __restrict__ be2,
    float* __restrict__ sa, float* __restrict__ sb, float invN,
    u16* __restrict__ hbOut, float* __restrict__ hOut, int writeF,
    int Nrows, int ntiles) {
    constexpr int KD = 128;
    constexpr u32 STR = 256;
    __shared__ u16 s_A[2][128 * KD];     // 64KB: z staging, then packed bn(t1)
    __shared__ u16 s_B[2][128 * KD];     // 64KB: W1, then W2
    __shared__ float s_red[2][8][128];   // 8KB
    __shared__ float s_sc[128], s_sh[128];
    cg::grid_group grid = cg::this_grid();
    const int t = threadIdx.x;
    const int l = t & 63, w = t >> 6;
    const int c0 = l & 15;
    const u32 kOffB = (u32)(l >> 4) * 16u;
    const u32 rA_row = w * 16 + c0;
    const int rgrp = (l >> 4) << 2;
    constexpr int KCB = KD / 8;              // 16 uint4 chunks/row
    constexpr int NAU = 128 * KCB / 512;     // 4

    // ---- phase A: stage W1; per tile stage z, MFMA1 -> acc1 (regs), stats sa
#pragma unroll
    for (int i = 0; i < NAU; i++) {
        int idx = i * 512 + t;
        int c = idx / KCB, kc = idx % KCB;
        u32 off = swz(c, kc * 16, STR);
        *(uint4*)((char*)s_B[0] + off) = *(const uint4*)(W1hi + (size_t)c * KD + kc * 8);
        *(uint4*)((char*)s_B[1] + off) = *(const uint4*)(W1lo + (size_t)c * KD + kc * 8);
    }

    f32x4 acc1[2][8];
#pragma unroll
    for (int k = 0; k < 2; k++)
#pragma unroll
        for (int n = 0; n < 8; n++) acc1[k][n] = (f32x4){0.f, 0.f, 0.f, 0.f};

#pragma unroll
    for (int k = 0; k < 2; k++) {
        int tile = blockIdx.x + k * gridDim.x;
        if (tile < ntiles) {
#pragma unroll
            for (int i = 0; i < NAU; i++) {
                int idx = i * 512 + t;
                int r = idx / KCB, kc = idx % KCB;
                int gr = tile * 128 + r;
                uint4 vh = {0, 0, 0, 0}, vl = {0, 0, 0, 0};
                if (gr < Nrows) {
                    vh = *(const uint4*)(zhi + (size_t)gr * KD + kc * 8);
                    vl = *(const uint4*)(zlo + (size_t)gr * KD + kc * 8);
                }
                u32 off = swz(r, kc * 16, STR);
                *(uint4*)((char*)s_A[0] + off) = vh;
                *(uint4*)((char*)s_A[1] + off) = vl;
            }
            __syncthreads();
#pragma unroll
            for (int kk = 0; kk < KD / 32; kk++) {
                u32 kb = kk * 64 + kOffB;
                bf16x8 ah = *(const bf16x8*)((char*)s_A[0] + swz(rA_row, kb, STR));
                bf16x8 al = *(const bf16x8*)((char*)s_A[1] + swz(rA_row, kb, STR));
#pragma unroll
                for (int n = 0; n < 8; n++) {
                    u32 ob = swz(n * 16 + c0, kb, STR);
                    bf16x8 bh = *(const bf16x8*)((char*)s_B[0] + ob);
                    bf16x8 bl = *(const bf16x8*)((char*)s_B[1] + ob);
                    acc1[k][n] = __builtin_amdgcn_mfma_f32_16x16x32_bf16(ah, bh, acc1[k][n], 0, 0, 0);
                    acc1[k][n] = __builtin_amdgcn_mfma_f32_16x16x32_bf16(al, bh, acc1[k][n], 0, 0, 0);
                    acc1[k][n] = __builtin_amdgcn_mfma_f32_16x16x32_bf16(ah, bl, acc1[k][n], 0, 0, 0);
                }
            }
            const int rbase = tile * 128 + w * 16 + rgrp;
#pragma unroll
            for (int n = 0; n < 8; n++) {
                const int colc = n * 16 + c0;
                const float bv = b1[colc];
                float s = 0.f, q = 0.f;
#pragma unroll
                for (int j = 0; j < 4; j++) {
                    float v = acc1[k][n][j] + bv;
                    acc1[k][n][j] = v;
                    if (rbase + j < Nrows) { s += v; q += v * v; }
                }
                s += __shfl_xor(s, 16); s += __shfl_xor(s, 32);
                q += __shfl_xor(q, 16); q += __shfl_xor(q, 32);
                if (l < 16) {
                    s_red[0][w][n * 16 + l] = s;
                    s_red[1][w][n * 16 + l] = q;
                }
            }
            __syncthreads();
            if (t < 128) {
                float S = 0.f, Q = 0.f;
#pragma unroll
                for (int ww = 0; ww < 8; ww++) { S += s_red[0][ww][t]; Q += s_red[1][ww][t]; }
                atomAddF(&sa[t], S);
                atomAddF(&sa[HH + t], Q);
            }
            __syncthreads();
        }
    }
    grid.sync();

    // ---- phase B: BN1 finalize; stage W2; per tile pack bn-relu(acc1)->LDS,
    //      MFMA2 -> acc2 (+b2), stats sb
    if (t < 128) {
        float m = sa[t] * invN;
        float var = sa[128 + t] * invN - m * m;
        float s = g1[t] * rsqrtf(var + 1e-5f);
        s_sc[t] = s;
        s_sh[t] = be1[t] - m * s;
    }
#pragma unroll
    for (int i = 0; i < NAU; i++) {
        int idx = i * 512 + t;
        int c = idx / KCB, kc = idx % KCB;
        u32 off = swz(c, kc * 16, STR);
        *(uint4*)((char*)s_B[0] + off) = *(const uint4*)(W2hi + (size_t)c * KD + kc * 8);
        *(uint4*)((char*)s_B[1] + off) = *(const uint4*)(W2lo + (size_t)c * KD + kc * 8);
    }
    __syncthreads();

    f32x4 acc2[2][8];
#pragma unroll
    for (int k = 0; k < 2; k++)
#pragma unroll
        for (int n = 0; n < 8; n++) acc2[k][n] = (f32x4){0.f, 0.f, 0.f, 0.f};

#pragma unroll
    for (int k = 0; k < 2; k++) {
        int tile = blockIdx.x + k * gridDim.x;
        if (tile < ntiles) {
            // pack bn-relu(t1) into A-operand layout (2B swizzled writes)
#pragma unroll
            for (int n = 0; n < 8; n++) {
                const int colc = n * 16 + c0;
                const float sc = s_sc[colc], sh = s_sh[colc];
#pragma unroll
                for (int j = 0; j < 4; j++) {
                    int rloc = w * 16 + rgrp + j;
                    float v = fmaxf(acc1[k][n][j] * sc + sh, 0.f);
                    u16 hi, lo;
                    split2(v, hi, lo);
                    u32 off = swz(rloc, (u32)colc * 2, STR);
                    *(u16*)((char*)s_A[0] + off) = hi;
                    *(u16*)((char*)s_A[1] + off) = lo;
                }
            }
            __syncthreads();
#pragma unroll
            for (int kk = 0; kk < KD / 32; kk++) {
                u32 kb = kk * 64 + kOffB;
                bf16x8 ah = *(const bf16x8*)((char*)s_A[0] + swz(rA_row, kb, STR));
                bf16x8 al = *(const bf16x8*)((char*)s_A[1] + swz(rA_row, kb, STR));
#pragma unroll
                for (int n = 0; n < 8; n++) {
                    u32 ob = swz(n * 16 + c0, kb, STR);
                    bf16x8 bh = *(const bf16x8*)((char*)s_B[0] + ob);
                    bf16x8 bl = *(const bf16x8*)((char*)s_B[1] + ob);
                    acc2[k][n] = __builtin_amdgcn_mfma_f32_16x16x32_bf16(ah, bh, acc2[k][n], 0, 0, 0);
                    acc2[k][n] = __builtin_amdgcn_mfma_f32_16x16x32_bf16(al, bh, acc2[k][n], 0, 0, 0);
                    acc2[k][n] = __builtin_amdgcn_mfma_f32_16x16x32_bf16(ah, bl, acc2[k][n], 0, 0, 0);
                }
            }
            const int rbase = tile * 128 + w * 16 + rgrp;
#pragma unroll
            for (int n = 0; n < 8; n++) {
                const int colc = n * 16 + c0;
                const float bv = b2[colc];
                float s = 0.f, q = 0.f;
#pragma unroll
                for (int j = 0; j < 4; j++) {
                    float v = acc2[k][n][j] + bv;
                    acc2[k][n][j] = v;
                    if (rbase + j < Nrows) { s += v; q += v * v; }
                }
                s += __shfl_xor(s, 16); s += __shfl_xor(s, 32);
                q += __shfl_xor(q, 16); q += __shfl_xor(q, 32);
                if (l < 16) {
                    s_red[0][w][n * 16 + l] = s;
                    s_red[1][w][n * 16 + l] = q;
                }
            }
            __syncthreads();
            if (t < 128) {
                float S = 0.f, Q = 0.f;
#pragma unroll
                for (int ww = 0; ww < 8; ww++) { S += s_red[0][ww][t]; Q += s_red[1][ww][t]; }
                atomAddF(&sb[t], S);
                atomAddF(&sb[HH + t], Q);
            }
            __syncthreads();
        }
    }
    grid.sync();

    // ---- phase C: BN2 finalize; h = relu(bn(t2)) from regs -> hb (+h f32)
    if (t < 128) {
        float m = sb[t] * invN;
        float var = sb[128 + t] * invN - m * m;
        float s = g2[t] * rsqrtf(var + 1e-5f);
        s_sc[t] = s;
        s_sh[t] = be2[t] - m * s;
    }
    __syncthreads();
#pragma unroll
    for (int k = 0; k < 2; k++) {
        int tile = blockIdx.x + k * gridDim.x;
        if (tile < ntiles) {
            const int rbase = tile * 128 + w * 16 + rgrp;
#pragma unroll
            for (int n = 0; n < 8; n++) {
                const int colc = n * 16 + c0;
                const float sc = s_sc[colc], sh = s_sh[colc];
#pragma unroll
                for (int j = 0; j < 4; j++) {
                    int gr = rbase + j;
                    if (gr < Nrows) {
                        float v = fmaxf(acc2[k][n][j] * sc + sh, 0.f);
                        hbOut[(size_t)gr * HH + colc] = f2bf(v);
                        if (writeF) hOut[(size_t)gr * HH + colc] = v;
                    }
                }
            }
        }
    }
}

// ---------------- gather: 2 waves/node, self from hb ----------------
__global__ __launch_bounds__(256) void k_gather(
    const u16* __restrict__ hb,
    const int* __restrict__ rowptr, const int* __restrict__ col,
    const float* __restrict__ ew, const float* __restrict__ eb,
    u16* __restrict__ zhi, u16* __restrict__ zlo, int N) {
    __shared__ float2 s_part[2][64];
    const int wv = threadIdx.x >> 6;
    const int lane = threadIdx.x & 63;
    const int node = blockIdx.x * 2 + (wv >> 1);
    const int hf = wv & 1;
    const int c2 = lane * 2;
    float2 acc = {0.f, 0.f};
    const bool valid = node < N;
    float2 ee = {0.f, 0.f};
    if (valid) {
        ee.x = ew[c2] + eb[c2];
        ee.y = ew[c2 + 1] + eb[c2 + 1];
        const int s = rowptr[node], eend = rowptr[node + 1];
        int e = s + hf;
        for (; e + 6 < eend; e += 8) {
            int s0 = col[e], s1 = col[e + 2], s2 = col[e + 4], s3 = col[e + 6];
            u32 u0 = *(const u32*)(hb + (size_t)s0 * HH + c2);
            u32 u1 = *(const u32*)(hb + (size_t)s1 * HH + c2);
            u32 u2 = *(const u32*)(hb + (size_t)s2 * HH + c2);
            u32 u3 = *(const u32*)(hb + (size_t)s3 * HH + c2);
            acc.x += fmaxf(bf2f_lo(u0) + ee.x, 0.f) + fmaxf(bf2f_lo(u1) + ee.x, 0.f) +
                     fmaxf(bf2f_lo(u2) + ee.x, 0.f) + fmaxf(bf2f_lo(u3) + ee.x, 0.f);
            acc.y += fmaxf(bf2f_hi(u0) + ee.y, 0.f) + fmaxf(bf2f_hi(u1) + ee.y, 0.f) +
                     fmaxf(bf2f_hi(u2) + ee.y, 0.f) + fmaxf(bf2f_hi(u3) + ee.y, 0.f);
        }
        for (; e < eend; e += 2) {
            u32 u0 = *(const u32*)(hb + (size_t)col[e] * HH + c2);
            acc.x += fmaxf(bf2f_lo(u0) + ee.x, 0.f);
            acc.y += fmaxf(bf2f_hi(u0) + ee.y, 0.f);
        }
    }
    if (hf) s_part[wv >> 1][lane] = acc;
    __syncthreads();
    if (!hf && valid) {
        float2 p = s_part[wv >> 1][lane];
        u32 un = *(const u32*)(hb + (size_t)node * HH + c2);
        float zx = bf2f_lo(un) + acc.x + p.x;
        float zy = bf2f_hi(un) + acc.y + p.y;
        u16 h0, h1, l0, l1;
        split2(zx, h0, l0);
        split2(zy, h1, l1);
        *(u32*)(zhi + (size_t)node * HH + c2) = (u32)h0 | ((u32)h1 << 16);
        *(u32*)(zlo + (size_t)node * HH + c2) = (u32)l0 | ((u32)l1 << 16);
    }
}

// ---------------- assign ----------------
__global__ __launch_bounds__(256) void k_assign(
    const float* __restrict__ h, const float* __restrict__ gum,
    const float* __restrict__ w1, const float* __restrict__ b1,
    const float* __restrict__ w2, const float* __restrict__ b2,
    float* __restrict__ assign, int N) {
    __shared__ float s_w1[128 * 64];
    __shared__ float s_w2[64 * 8];
    __shared__ float s_h[32][128];
    __shared__ float s_hid[32][64];
    const int t = threadIdx.x;
    const int n0 = blockIdx.x * 32;
    for (int i = t; i < 128 * 64; i += 256) s_w1[i] = w1[i];
    for (int i = t; i < 512; i += 256) s_w2[i] = w2[i];
    for (int i = t; i < 32 * 32; i += 256) {
        int r = i >> 5, c4 = (i & 31) << 2;
        int gn = n0 + r;
        float4 v = {0.f, 0.f, 0.f, 0.f};
        if (gn < N) v = *(const float4*)(h + (size_t)gn * HH + c4);
        *(float4*)(&s_h[r][c4]) = v;
    }
    __syncthreads();
    for (int o = t; o < 32 * 64; o += 256) {
        int nn = o >> 6, j = o & 63;
        float acc = b1[j];
        for (int k = 0; k < 128; k++) acc = fmaf(s_h[nn][k], s_w1[k * 64 + j], acc);
        s_hid[nn][j] = fmaxf(acc, 0.f);
    }
    __syncthreads();
    int nn = t >> 3, kk = t & 7;
    int gn = n0 + nn;
    float a = b2[kk];
    for (int j = 0; j < 64; j++) a = fmaf(s_hid[nn][j], s_w2[j * 8 + kk], a);
    if (gn < N) a += gum[(size_t)gn * 8 + kk];
    float m = a;
    m = fmaxf(m, __shfl_xor(m, 1));
    m = fmaxf(m, __shfl_xor(m, 2));
    m = fmaxf(m, __shfl_xor(m, 4));
    float e = expf(a - m);
    float s = e;
    s += __shfl_xor(s, 1); s += __shfl_xor(s, 2); s += __shfl_xor(s, 4);
    if (gn < N) assign[(size_t)gn * 8 + kk] = e / s;
}

// ---------------- tail ----------------
__device__ __forceinline__ int lowerb(const int* __restrict__ arr, int n, int val) {
    int lo = 0, hi = n;
    while (lo < hi) {
        int mid = (lo + hi) >> 1;
        if (arr[mid] < val) lo = mid + 1;
        else hi = mid;
    }
    return lo;
}

__global__ __launch_bounds__(1024) void k_pool(
    const float* __restrict__ h, const float* __restrict__ assign,
    const int* __restrict__ batch, float* __restrict__ gmean,
    float* __restrict__ num, float* __restrict__ den, int N) {
    __shared__ float4 s_num[4][8][32];
    __shared__ float4 s_gm[4][32];
    __shared__ float s_den[4][8];
    const int g = blockIdx.x;
    const int t = threadIdx.x;
    const int ns = t >> 8;
    const int k = (t >> 5) & 7;
    const int lane = t & 31;
    const int c4 = lane << 2;
    const int start = lowerb(batch, N, g);
    const int end = lowerb(batch, N, g + 1);
    float4 an = {0.f, 0.f, 0.f, 0.f};
    float4 gm = {0.f, 0.f, 0.f, 0.f};
    float ad = 0.f;
    for (int n = start + ns; n < end; n += 4) {
        float a = assign[(size_t)n * 8 + k];
        const float4 hv = *(const float4*)(h + (size_t)n * HH + c4);
        an.x = fmaf(a, hv.x, an.x);
        an.y = fmaf(a, hv.y, an.y);
        an.z = fmaf(a, hv.z, an.z);
        an.w = fmaf(a, hv.w, an.w);
        if (k == 0) { gm.x += hv.x; gm.y += hv.y; gm.z += hv.z; gm.w += hv.w; }
        ad += a;
    }
    s_num[ns][k][lane] = an;
    if (k == 0) s_gm[ns][lane] = gm;
    if (lane == 0) s_den[ns][k] = ad;
    __syncthreads();
    if (t < 256) {
        float4 a0 = s_num[0][k][lane], a1 = s_num[1][k][lane];
        float4 a2 = s_num[2][k][lane], a3 = s_num[3][k][lane];
        float4 o = {a0.x + a1.x + a2.x + a3.x, a0.y + a1.y + a2.y + a3.y,
                    a0.z + a1.z + a2.z + a3.z, a0.w + a1.w + a2.w + a3.w};
        *(float4*)(num + ((size_t)g * 8 + k) * HH + c4) = o;
        if (t < 32) {
            float4 g0 = s_gm[0][lane], g1 = s_gm[1][lane];
            float4 g2 = s_gm[2][lane], g3 = s_gm[3][lane];
            int cnt = end - start;
            float inv = 1.f / (float)(cnt > 0 ? cnt : 1);
            float4 om = {(g0.x + g1.x + g2.x + g3.x) * inv,
                         (g0.y + g1.y + g2.y + g3.y) * inv,
                         (g0.z + g1.z + g2.z + g3.z) * inv,
                         (g0.w + g1.w + g2.w + g3.w) * inv};
            *(float4*)(gmean + (size_t)g * HH + c4) = om;
        }
        if (t < 8) den[(size_t)g * 8 + t] =
            s_den[0][t] + s_den[1][t] + s_den[2][t] + s_den[3][t];
    }
}

__global__ void k_blob(const float* __restrict__ num, const float* __restrict__ den,
                       const float* __restrict__ w, const float* __restrict__ b,
                       const float* __restrict__ lg, const float* __restrict__ lb,
                       float* __restrict__ blobs) {
    const int gk = blockIdx.x;
    const int c = threadIdx.x;  // 128
    __shared__ float srow[128];
    __shared__ float red[4];
    float d = den[gk] + 1e-8f;
    srow[c] = num[(size_t)gk * HH + c] / d;
    __syncthreads();
    float acc = b[c];
    for (int j = 0; j < 128; j++) acc = fmaf(srow[j], w[j * HH + c], acc);
    float y = fmaxf(acc, 0.f);
    float s = y, q = y * y;
    for (int off = 32; off > 0; off >>= 1) {
        s += __shfl_down(s, off);
        q += __shfl_down(q, off);
    }
    if ((c & 63) == 0) { red[(c >> 6) * 2] = s; red[(c >> 6) * 2 + 1] = q; }
    __syncthreads();
    float S = red[0] + red[2], Q = red[1] + red[3];
    float m = S * (1.f / 128.f);
    float var = Q * (1.f / 128.f) - m * m;
    blobs[(size_t)gk * HH + c] = (y - m) * rsqrtf(var + 1e-5f) * lg[c] + lb[c];
}

__global__ void k_clf1(const float* __restrict__ gmean, const float* __restrict__ blobs,
                       const float* __restrict__ w, const float* __restrict__ bias,
                       float* __restrict__ t4, float* __restrict__ stats) {
    int g = blockIdx.x;
    int c = threadIdx.x;  // 128
    __shared__ float s[256];
    float m = blobs[((size_t)g * 8) * HH + c];
#pragma unroll
    for (int k = 1; k < 8; k++) m = fmaxf(m, blobs[((size_t)g * 8 + k) * HH + c]);
    s[c] = gmean[(size_t)g * HH + c];
    s[128 + c] = m;
    __syncthreads();
    float acc = bias[c];
    for (int j = 0; j < 256; j++) acc = fmaf(s[j], w[j * HH + c], acc);
    t4[(size_t)g * HH + c] = acc;
    atomAddF(&stats[c], acc);
    atomAddF(&stats[HH + c], acc * acc);
}

__global__ void k_clf2(const float* __restrict__ t4, const float* __restrict__ stats,
                       const float* __restrict__ g_, const float* __restrict__ b_,
                       float invG, const float* __restrict__ w,
                       const float* __restrict__ bias, float* __restrict__ out) {
    int g = blockIdx.x;
    int t = threadIdx.x;  // 128
    __shared__ float s[128];
    float m = stats[t] * invG;
    float var = stats[128 + t] * invG - m * m;
    float sc = g_[t] * rsqrtf(var + 1e-5f);
    float sh = b_[t] - m * sc;
    s[t] = fmaxf(t4[(size_t)g * HH + t] * sc + sh, 0.f);
    __syncthreads();
    if (t < 10) {
        float acc = bias[t];
        for (int j = 0; j < 128; j++) acc = fmaf(s[j], w[j * 10 + t], acc);
        out[(size_t)g * 10 + t] = acc;
    }
}

extern "C" void kernel_launch(void* const* d_in, const int* in_sizes, int n_in,
                              void* d_out, int out_size, void* d_ws, size_t ws_size,
                              hipStream_t stream) {
    const float* x      = (const float*)d_in[0];
    const int*   ei     = (const int*)d_in[1];
    const int*   batch  = (const int*)d_in[2];
    const float* gumbel = (const float*)d_in[3];
    const float* inp_w  = (const float*)d_in[4];
    const float* inp_b  = (const float*)d_in[5];
    const float* elin_w = (const float*)d_in[6];
    const float* elin_b = (const float*)d_in[7];
    const float* mlp1_w = (const float*)d_in[8];
    const float* mlp1_b = (const float*)d_in[9];
    const float* mlpbn_g = (const float*)d_in[10];
    const float* mlpbn_b = (const float*)d_in[11];
    const float* mlp2_w = (const float*)d_in[12];
    const float* mlp2_b = (const float*)d_in[13];
    const float* bn_g   = (const float*)d_in[14];
    const float* bn_b   = (const float*)d_in[15];
    const float* bh1_w  = (const float*)d_in[16];
    const float* bh1_b  = (const float*)d_in[17];
    const float* bh2_w  = (const float*)d_in[18];
    const float* bh2_b  = (const float*)d_in[19];
    const float* bm_w   = (const float*)d_in[20];
    const float* bm_b   = (const float*)d_in[21];
    const float* ln_g   = (const float*)d_in[22];
    const float* ln_b   = (const float*)d_in[23];
    const float* clf1_w = (const float*)d_in[24];
    const float* clf1_b = (const float*)d_in[25];
    const float* clfbn_g = (const float*)d_in[26];
    const float* clfbn_b = (const float*)d_in[27];
    const float* clf2_w = (const float*)d_in[28];
    const float* clf2_b = (const float*)d_in[29];
    float* out = (float*)d_out;

    const int N = in_sizes[0] / 64;
    const int E = in_sizes[1] / 2;
    const int G = out_size / 10;

    float* ws = (float*)d_ws;
    float* h      = ws;                                  // N*128
    float* zbuf   = h + (size_t)N * HH;                  // N*128 f32 (multi-use)
    float* t1     = zbuf + (size_t)N * HH;               // N*128 (hb home)
    float* assign = t1 + (size_t)N * HH;                 // N*8
    float* gmean  = assign + (size_t)N * 8;              // G*128
    float* num    = gmean + (size_t)G * HH;              // G*8*128
    float* den    = num + (size_t)G * 8 * HH;            // G*8
    float* blobs  = den + (size_t)G * 8;                 // G*8*128
    float* t4     = blobs + (size_t)G * 8 * HH;          // G*128
    float* statsA = t4 + (size_t)G * HH;                 // 7*256 stats buffers
    u16* Whi = (u16*)(statsA + 7 * 256);                 // WTOT
    u16* Wlo = Whi + WTOT;                               // WTOT
    int* rowptr = (int*)(Wlo + WTOT);                    // N+1
    int* cursor = rowptr + (N + 1);                      // N (also deg)
    int* colidx = cursor + N;                            // E
    int* bsum   = colidx + E;                            // 256
    int* boff   = bsum + 256;                            // 256
    // aliases (disjoint lifetimes):
    u16* hb  = (u16*)t1;          // bf16 h; persists across each layer
    u16* xhi = (u16*)zbuf;        // x pre-split, dead after input gemm
    u16* xlo = xhi + (size_t)N * 64;
    u16* zhi = (u16*)zbuf;        // gather output, dead after k_layer phase A
    u16* zlo = zhi + (size_t)N * HH;

    const dim3 B256(256), B128(128), B512(512), B1024(1024);
    const int ntiles = (N + 127) / 128;
    const int gg = ntiles < 256 ? ntiles : 256;
    const int nch = (N + 255) / 256;
    const int e4 = (E + 4 * 256 - 1) / (4 * 256);
    const float invN = 1.f / (float)N;
    const float invG = 1.f / (float)G;

    // weight prep + CSR build + stats clear
    k_prep<<<7, B256, 0, stream>>>(inp_w, mlp1_w, mlp2_w, Whi, Wlo);
    hipMemsetAsync(cursor, 0, (size_t)N * sizeof(int), stream);
    hipMemsetAsync(statsA, 0, 7 * 256 * sizeof(float), stream);
    k_hist<<<e4, B256, 0, stream>>>(ei, cursor, E);
    k_bsum<<<nch, B256, 0, stream>>>(cursor, bsum, N);
    k_scan1<<<1, B256, 0, stream>>>(bsum, boff, rowptr + N, nch);
    k_scan2<<<nch, B256, 0, stream>>>(cursor, boff, rowptr, cursor, N);
    k_fill<<<e4, B256, 0, stream>>>(ei, cursor, colidx, E);
    k_split<<<(N * 16 + 255) / 256, B256, 0, stream>>>(x, xhi, xlo, N * 16);

    // hb = bf16(x @ inp_w + inp_b)
    k_ingemm<<<gg, B512, 0, stream>>>(xhi, xlo, Whi, Wlo, inp_b, hb, N, ntiles);

    for (int l = 0; l < 3; l++) {
        float* sa = statsA + (size_t)(2 * l) * 256;
        float* sb = sa + 256;
        k_gather<<<(N + 1) / 2, B256, 0, stream>>>(hb, rowptr, colidx,
                                                   elin_w + l * HH, elin_b + l * HH,
                                                   zhi, zlo, N);
        const u16* W1h = Whi + 8192 + (size_t)l * 16384;
        const u16* W1l = Wlo + 8192 + (size_t)l * 16384;
        const u16* W2h = Whi + 8192 + (size_t)(3 + l) * 16384;
        const u16* W2l = Wlo + 8192 + (size_t)(3 + l) * 16384;
        const float* b1p = mlp1_b + l * HH;
        const float* g1p = mlpbn_g + l * HH;
        const float* be1p = mlpbn_b + l * HH;
        const float* b2p = mlp2_b + l * HH;
        const float* g2p = bn_g + l * HH;
        const float* be2p = bn_b + l * HH;
        const u16* zhc = zhi; const u16* zlc = zlo;
        u16* hbp = hb;
        float* hp = h;
        int writeF = (l == 2) ? 1 : 0;
        float invNv = invN;
        int Nv = N, ntv = ntiles;
        void* args[] = {(void*)&zhc, (void*)&zlc, (void*)&W1h, (void*)&W1l,
                        (void*)&b1p, (void*)&g1p, (void*)&be1p,
                        (void*)&W2h, (void*)&W2l, (void*)&b2p, (void*)&g2p,
                        (void*)&be2p, (void*)&sa, (void*)&sb, (void*)&invNv,
                        (void*)&hbp, (void*)&hp, (void*)&writeF,
                        (void*)&Nv, (void*)&ntv};
        hipLaunchCooperativeKernel((const void*)k_layer, dim3(gg), dim3(512),
                                   args, 0, stream);
    }

    k_assign<<<(N + 31) / 32, B256, 0, stream>>>(h, gumbel, bh1_w, bh1_b, bh2_w, bh2_b, assign, N);
    k_pool<<<G, B1024, 0, stream>>>(h, assign, batch, gmean, num, den, N);
    k_blob<<<G * 8, B128, 0, stream>>>(num, den, bm_w, bm_b, ln_g, ln_b, blobs);
    float* sc_ = statsA + 6 * 256;
    k_clf1<<<G, B128, 0, stream>>>(gmean, blobs, clf1_w, clf1_b, t4, sc_);
    k_clf2<<<G, B128, 0, stream>>>(t4, sc_, clfbn_g, clfbn_b, invG, clf2_w, clf2_b, out);
}

// Round 11
// 508.587 us; speedup vs baseline: 1.3450x; 1.3450x over previous
//
#include <hip/hip_runtime.h>
#include <hip/hip_bf16.h>

// ---------------------------------------------------------------------------
// SoftBlobGIN round 11: revert R10's cooperative fusion (occupancy/LDS-conflict
// bound). R9 structure + 8-deep gather unroll + direct-f32 input GEMM (MODE 0).
// ---------------------------------------------------------------------------

#define HH 128
typedef unsigned short u16;
typedef unsigned int u32;
typedef __attribute__((ext_vector_type(8))) short bf16x8;
typedef __attribute__((ext_vector_type(4))) float f32x4;

__device__ __forceinline__ void atomAddF(float* p, float v) { unsafeAtomicAdd(p, v); }

__device__ __forceinline__ u16 f2bf(float f) {          // RNE f32->bf16
    u32 u = __float_as_uint(f);
    u += 0x7fffu + ((u >> 16) & 1u);
    return (u16)(u >> 16);
}
__device__ __forceinline__ float bf2f_lo(u32 u) { return __uint_as_float(u << 16); }
__device__ __forceinline__ float bf2f_hi(u32 u) { return __uint_as_float(u & 0xffff0000u); }
__device__ __forceinline__ void split2(float v, u16& hi, u16& lo) {
    u16 h_ = f2bf(v);
    float hf = __uint_as_float(((u32)h_) << 16);
    hi = h_;
    lo = f2bf(v - hf);
}
__device__ __forceinline__ u32 swz(u32 row, u32 kByte, u32 strideB) {
    return (row * strideB + kByte) ^ ((row & 7u) << 4);
}

#define WTOT (8192 + 6 * 16384)

// ---------------- weight prep ----------------
__global__ void k_prep(const float* __restrict__ inp_w, const float* __restrict__ m1,
                       const float* __restrict__ m2, u16* __restrict__ Whi,
                       u16* __restrict__ Wlo) {
    int b = blockIdx.x;  // 0..6
    int t = threadIdx.x; // 256
    if (b == 0) {
        for (int idx = t; idx < 128 * 64; idx += 256) {
            int c = idx >> 6, k = idx & 63;
            u16 hi, lo;
            split2(inp_w[k * 128 + c], hi, lo);
            Whi[idx] = hi; Wlo[idx] = lo;
        }
    } else {
        const float* W = (b <= 3) ? m1 + (size_t)(b - 1) * 16384
                                  : m2 + (size_t)(b - 4) * 16384;
        u16* dh = Whi + 8192 + (size_t)(b - 1) * 16384;
        u16* dl = Wlo + 8192 + (size_t)(b - 1) * 16384;
        for (int idx = t; idx < 16384; idx += 256) {
            int c = idx >> 7, k = idx & 127;
            u16 hi, lo;
            split2(W[k * 128 + c], hi, lo);
            dh[idx] = hi; dl[idx] = lo;
        }
    }
}

// ---------------- CSR build (4 edges/thread) ----------------
__global__ void k_hist(const int* __restrict__ ei, int* __restrict__ deg, int E) {
    int i4 = blockIdx.x * 256 + threadIdx.x;
    int e0 = i4 * 4;
    if (e0 + 3 < E) {
        int4 d = *(const int4*)(ei + E + e0);
        atomicAdd(&deg[d.x], 1);
        atomicAdd(&deg[d.y], 1);
        atomicAdd(&deg[d.z], 1);
        atomicAdd(&deg[d.w], 1);
    } else {
        for (int e = e0; e < E; e++) atomicAdd(&deg[ei[E + e]], 1);
    }
}

__global__ void k_bsum(const int* __restrict__ deg, int* __restrict__ bsum, int N) {
    int t = threadIdx.x;
    int i = blockIdx.x * 256 + t;
    int v = (i < N) ? deg[i] : 0;
    for (int o = 32; o; o >>= 1) v += __shfl_down(v, o);
    __shared__ int ws_[4];
    if ((t & 63) == 0) ws_[t >> 6] = v;
    __syncthreads();
    if (t == 0) bsum[blockIdx.x] = ws_[0] + ws_[1] + ws_[2] + ws_[3];
}

__global__ void k_scan1(const int* __restrict__ bsum, int* __restrict__ boff,
                        int* __restrict__ rowptrN, int nch) {
    int t = threadIdx.x;  // 256
    int v = (t < nch) ? bsum[t] : 0;
    int l = t & 63, w = t >> 6;
    int sv = v;
    for (int o = 1; o < 64; o <<= 1) { int u = __shfl_up(sv, o); if (l >= o) sv += u; }
    __shared__ int wsum[4];
    if (l == 63) wsum[w] = sv;
    __syncthreads();
    int add = 0;
    for (int j = 0; j < w; j++) add += wsum[j];
    if (t < nch) boff[t] = sv - v + add;
    if (t == nch - 1) *rowptrN = sv + add;
}

__global__ void k_scan2(const int* __restrict__ deg, const int* __restrict__ boff,
                        int* __restrict__ rowptr, int* __restrict__ cursor, int N) {
    int b = blockIdx.x, t = threadIdx.x, i = b * 256 + t;
    int v = (i < N) ? deg[i] : 0;
    int l = t & 63, w = t >> 6;
    int sv = v;
    for (int o = 1; o < 64; o <<= 1) { int u = __shfl_up(sv, o); if (l >= o) sv += u; }
    __shared__ int wsum[4];
    if (l == 63) wsum[w] = sv;
    __syncthreads();
    int add = boff[b];
    for (int j = 0; j < w; j++) add += wsum[j];
    if (i < N) { int e = sv - v + add; rowptr[i] = e; cursor[i] = e; }
}

__global__ void k_fill(const int* __restrict__ ei, int* __restrict__ cursor,
                       int* __restrict__ col, int E) {
    int i4 = blockIdx.x * 256 + threadIdx.x;
    int e0 = i4 * 4;
    if (e0 + 3 < E) {
        int4 s = *(const int4*)(ei + e0);
        int4 d = *(const int4*)(ei + E + e0);
        int p0 = atomicAdd(&cursor[d.x], 1);
        int p1 = atomicAdd(&cursor[d.y], 1);
        int p2 = atomicAdd(&cursor[d.z], 1);
        int p3 = atomicAdd(&cursor[d.w], 1);
        col[p0] = s.x;
        col[p1] = s.y;
        col[p2] = s.z;
        col[p3] = s.w;
    } else {
        for (int e = e0; e < E; e++) {
            int pos = atomicAdd(&cursor[ei[E + e]], 1);
            col[pos] = ei[e];
        }
    }
}

// ---------------- persistent-B split-precision MFMA GEMM (512 thr, 128-row) -
// MODE 0: f32 input (split in staging) | MODE 1: f32 input + bn-relu |
// MODE 2: pre-split bf16 hi/lo input
template <int KD, int MODE, bool STATS, bool FOUT, bool BOUT>
__global__ __launch_bounds__(512) void k_mgemm(
    const float* __restrict__ inf, const u16* __restrict__ inhi,
    const u16* __restrict__ inlo, const u16* __restrict__ Whi,
    const u16* __restrict__ Wlo, const float* __restrict__ bias,
    const float* __restrict__ statsIn, const float* __restrict__ gamma,
    const float* __restrict__ beta, float invN,
    float* __restrict__ out, u16* __restrict__ outb,
    float* __restrict__ statsOut, int Nrows, int ntiles) {
    __shared__ u16 s_Ahi[128 * KD];
    __shared__ u16 s_Alo[128 * KD];
    __shared__ u16 s_Bhi[128 * KD];
    __shared__ u16 s_Blo[128 * KD];
    __shared__ float s_red[2][8][128];
    __shared__ float s_sc[128], s_sh[128];
    const int t = threadIdx.x;
    constexpr u32 STR = KD * 2;
    constexpr int KCB = KD / 8;
    constexpr int KCF = KD / 4;
    constexpr int NAU = (128 * KCB) / 512;
    constexpr int NAF = (128 * KCF) / 512;
    constexpr int NB  = (128 * KCB) / 512;

#pragma unroll
    for (int i = 0; i < NB; i++) {
        int idx = i * 512 + t;
        int c = idx / KCB, kc = idx % KCB;
        u32 off = swz(c, kc * 16, STR);
        *(uint4*)((char*)s_Bhi + off) = *(const uint4*)(Whi + (size_t)c * KD + kc * 8);
        *(uint4*)((char*)s_Blo + off) = *(const uint4*)(Wlo + (size_t)c * KD + kc * 8);
    }
    if (MODE == 1 && t < 128) {
        float m = statsIn[t] * invN;
        float var = statsIn[128 + t] * invN - m * m;
        float s = gamma[t] * rsqrtf(var + 1e-5f);
        s_sc[t] = s;
        s_sh[t] = beta[t] - m * s;
    }
    __syncthreads();

    float4 rf[MODE <= 1 ? NAF : 1];
    uint4 rh[MODE == 2 ? NAU : 1], rl[MODE == 2 ? NAU : 1];
    int tile = blockIdx.x;
    if (tile < ntiles) {
        if (MODE <= 1) {
#pragma unroll
            for (int i = 0; i < NAF; i++) {
                int idx = i * 512 + t;
                int r = idx / KCF, kc = idx % KCF;
                int gr = tile * 128 + r;
                rf[i] = (gr < Nrows) ? *(const float4*)(inf + (size_t)gr * KD + kc * 4)
                                     : (float4){0.f, 0.f, 0.f, 0.f};
            }
        } else {
#pragma unroll
            for (int i = 0; i < NAU; i++) {
                int idx = i * 512 + t;
                int r = idx / KCB, kc = idx % KCB;
                int gr = tile * 128 + r;
                if (gr < Nrows) {
                    rh[i] = *(const uint4*)(inhi + (size_t)gr * KD + kc * 8);
                    rl[i] = *(const uint4*)(inlo + (size_t)gr * KD + kc * 8);
                } else {
                    rh[i] = (uint4){0, 0, 0, 0};
                    rl[i] = (uint4){0, 0, 0, 0};
                }
            }
        }
    }

    const int l = t & 63, w = t >> 6;
    const int c0 = l & 15;
    const u32 kOffB = (u32)(l >> 4) * 16u;
    const u32 rA_row = w * 16 + c0;

    for (; tile < ntiles; tile += gridDim.x) {
        if (MODE <= 1) {
#pragma unroll
            for (int i = 0; i < NAF; i++) {
                int idx = i * 512 + t;
                int r = idx / KCF, kc = idx % KCF;
                float4 v = rf[i];
                if (MODE == 1) {
                    int k0 = kc * 4;
                    v.x = fmaxf(v.x * s_sc[k0 + 0] + s_sh[k0 + 0], 0.f);
                    v.y = fmaxf(v.y * s_sc[k0 + 1] + s_sh[k0 + 1], 0.f);
                    v.z = fmaxf(v.z * s_sc[k0 + 2] + s_sh[k0 + 2], 0.f);
                    v.w = fmaxf(v.w * s_sc[k0 + 3] + s_sh[k0 + 3], 0.f);
                }
                u16 h0, h1, h2, h3, l0, l1, l2, l3;
                split2(v.x, h0, l0); split2(v.y, h1, l1);
                split2(v.z, h2, l2); split2(v.w, h3, l3);
                uint2 ph = {(u32)h0 | ((u32)h1 << 16), (u32)h2 | ((u32)h3 << 16)};
                uint2 pl = {(u32)l0 | ((u32)l1 << 16), (u32)l2 | ((u32)l3 << 16)};
                u32 off = swz(r, kc * 8, STR);
                *(uint2*)((char*)s_Ahi + off) = ph;
                *(uint2*)((char*)s_Alo + off) = pl;
            }
        } else {
#pragma unroll
            for (int i = 0; i < NAU; i++) {
                int idx = i * 512 + t;
                int r = idx / KCB, kc = idx % KCB;
                u32 off = swz(r, kc * 16, STR);
                *(uint4*)((char*)s_Ahi + off) = rh[i];
                *(uint4*)((char*)s_Alo + off) = rl[i];
            }
        }
        __syncthreads();

        int nxt = tile + gridDim.x;
        if (nxt < ntiles) {
            if (MODE <= 1) {
#pragma unroll
                for (int i = 0; i < NAF; i++) {
                    int idx = i * 512 + t;
                    int r = idx / KCF, kc = idx % KCF;
                    int gr = nxt * 128 + r;
                    rf[i] = (gr < Nrows) ? *(const float4*)(inf + (size_t)gr * KD + kc * 4)
                                         : (float4){0.f, 0.f, 0.f, 0.f};
                }
            } else {
#pragma unroll
                for (int i = 0; i < NAU; i++) {
                    int idx = i * 512 + t;
                    int r = idx / KCB, kc = idx % KCB;
                    int gr = nxt * 128 + r;
                    if (gr < Nrows) {
                        rh[i] = *(const uint4*)(inhi + (size_t)gr * KD + kc * 8);
                        rl[i] = *(const uint4*)(inlo + (size_t)gr * KD + kc * 8);
                    } else {
                        rh[i] = (uint4){0, 0, 0, 0};
                        rl[i] = (uint4){0, 0, 0, 0};
                    }
                }
            }
        }

        f32x4 acc[8];
#pragma unroll
        for (int n = 0; n < 8; n++) acc[n] = (f32x4){0.f, 0.f, 0.f, 0.f};
#pragma unroll
        for (int kk = 0; kk < KD / 32; kk++) {
            u32 kb = kk * 64 + kOffB;
            bf16x8 ah = *(const bf16x8*)((char*)s_Ahi + swz(rA_row, kb, STR));
            bf16x8 al = *(const bf16x8*)((char*)s_Alo + swz(rA_row, kb, STR));
#pragma unroll
            for (int n = 0; n < 8; n++) {
                u32 ob = swz(n * 16 + c0, kb, STR);
                bf16x8 bh = *(const bf16x8*)((char*)s_Bhi + ob);
                bf16x8 bl = *(const bf16x8*)((char*)s_Blo + ob);
                acc[n] = __builtin_amdgcn_mfma_f32_16x16x32_bf16(ah, bh, acc[n], 0, 0, 0);
                acc[n] = __builtin_amdgcn_mfma_f32_16x16x32_bf16(al, bh, acc[n], 0, 0, 0);
                acc[n] = __builtin_amdgcn_mfma_f32_16x16x32_bf16(ah, bl, acc[n], 0, 0, 0);
            }
        }

        const int rbase = tile * 128 + w * 16 + ((l >> 4) << 2);
#pragma unroll
        for (int n = 0; n < 8; n++) {
            const int colc = n * 16 + c0;
            const float bv = bias[colc];
            float s = 0.f, q = 0.f;
#pragma unroll
            for (int j = 0; j < 4; j++) {
                int gr = rbase + j;
                if (gr < Nrows) {
                    float v = acc[n][j] + bv;
                    if (FOUT) out[(size_t)gr * HH + colc] = v;
                    if (BOUT) outb[(size_t)gr * HH + colc] = f2bf(v);
                    s += v;
                    q += v * v;
                }
            }
            if (STATS) {
                s += __shfl_xor(s, 16); s += __shfl_xor(s, 32);
                q += __shfl_xor(q, 16); q += __shfl_xor(q, 32);
                if (l < 16) {
                    s_red[0][w][n * 16 + l] = s;
                    s_red[1][w][n * 16 + l] = q;
                }
            }
        }
        __syncthreads();
        if (STATS && t < 128) {
            float S = 0.f, Q = 0.f;
#pragma unroll
            for (int ww = 0; ww < 8; ww++) { S += s_red[0][ww][t]; Q += s_red[1][ww][t]; }
            atomAddF(&statsOut[t], S);
            atomAddF(&statsOut[HH + t], Q);
        }
    }
}

// ---------------- gather: 2 waves/node, 8-deep unroll, self from hb ---------
__global__ __launch_bounds__(256) void k_gather(
    const u16* __restrict__ hb,
    const int* __restrict__ rowptr, const int* __restrict__ col,
    const float* __restrict__ ew, const float* __restrict__ eb,
    u16* __restrict__ zhi, u16* __restrict__ zlo, int N) {
    __shared__ float2 s_part[2][64];
    const int wv = threadIdx.x >> 6;
    const int lane = threadIdx.x & 63;
    const int node = blockIdx.x * 2 + (wv >> 1);
    const int hf = wv & 1;
    const int c2 = lane * 2;
    float2 acc = {0.f, 0.f};
    const bool valid = node < N;
    float2 ee = {0.f, 0.f};
    if (valid) {
        ee.x = ew[c2] + eb[c2];
        ee.y = ew[c2 + 1] + eb[c2 + 1];
        const int s = rowptr[node], eend = rowptr[node + 1];
        int e = s + hf;
        for (; e + 14 < eend; e += 16) {
            int s0 = col[e], s1 = col[e + 2], s2 = col[e + 4], s3 = col[e + 6];
            int s4 = col[e + 8], s5 = col[e + 10], s6 = col[e + 12], s7 = col[e + 14];
            u32 u0 = *(const u32*)(hb + (size_t)s0 * HH + c2);
            u32 u1 = *(const u32*)(hb + (size_t)s1 * HH + c2);
            u32 u2 = *(const u32*)(hb + (size_t)s2 * HH + c2);
            u32 u3 = *(const u32*)(hb + (size_t)s3 * HH + c2);
            u32 u4 = *(const u32*)(hb + (size_t)s4 * HH + c2);
            u32 u5 = *(const u32*)(hb + (size_t)s5 * HH + c2);
            u32 u6 = *(const u32*)(hb + (size_t)s6 * HH + c2);
            u32 u7 = *(const u32*)(hb + (size_t)s7 * HH + c2);
            acc.x += fmaxf(bf2f_lo(u0) + ee.x, 0.f) + fmaxf(bf2f_lo(u1) + ee.x, 0.f) +
                     fmaxf(bf2f_lo(u2) + ee.x, 0.f) + fmaxf(bf2f_lo(u3) + ee.x, 0.f) +
                     fmaxf(bf2f_lo(u4) + ee.x, 0.f) + fmaxf(bf2f_lo(u5) + ee.x, 0.f) +
                     fmaxf(bf2f_lo(u6) + ee.x, 0.f) + fmaxf(bf2f_lo(u7) + ee.x, 0.f);
            acc.y += fmaxf(bf2f_hi(u0) + ee.y, 0.f) + fmaxf(bf2f_hi(u1) + ee.y, 0.f) +
                     fmaxf(bf2f_hi(u2) + ee.y, 0.f) + fmaxf(bf2f_hi(u3) + ee.y, 0.f) +
                     fmaxf(bf2f_hi(u4) + ee.y, 0.f) + fmaxf(bf2f_hi(u5) + ee.y, 0.f) +
                     fmaxf(bf2f_hi(u6) + ee.y, 0.f) + fmaxf(bf2f_hi(u7) + ee.y, 0.f);
        }
        for (; e + 6 < eend; e += 8) {
            int s0 = col[e], s1 = col[e + 2], s2 = col[e + 4], s3 = col[e + 6];
            u32 u0 = *(const u32*)(hb + (size_t)s0 * HH + c2);
            u32 u1 = *(const u32*)(hb + (size_t)s1 * HH + c2);
            u32 u2 = *(const u32*)(hb + (size_t)s2 * HH + c2);
            u32 u3 = *(const u32*)(hb + (size_t)s3 * HH + c2);
            acc.x += fmaxf(bf2f_lo(u0) + ee.x, 0.f) + fmaxf(bf2f_lo(u1) + ee.x, 0.f) +
                     fmaxf(bf2f_lo(u2) + ee.x, 0.f) + fmaxf(bf2f_lo(u3) + ee.x, 0.f);
            acc.y += fmaxf(bf2f_hi(u0) + ee.y, 0.f) + fmaxf(bf2f_hi(u1) + ee.y, 0.f) +
                     fmaxf(bf2f_hi(u2) + ee.y, 0.f) + fmaxf(bf2f_hi(u3) + ee.y, 0.f);
        }
        for (; e < eend; e += 2) {
            u32 u0 = *(const u32*)(hb + (size_t)col[e] * HH + c2);
            acc.x += fmaxf(bf2f_lo(u0) + ee.x, 0.f);
            acc.y += fmaxf(bf2f_hi(u0) + ee.y, 0.f);
        }
    }
    if (hf) s_part[wv >> 1][lane] = acc;
    __syncthreads();
    if (!hf && valid) {
        float2 p = s_part[wv >> 1][lane];
        u32 un = *(const u32*)(hb + (size_t)node * HH + c2);
        float zx = bf2f_lo(un) + acc.x + p.x;
        float zy = bf2f_hi(un) + acc.y + p.y;
        u16 h0, h1, l0, l1;
        split2(zx, h0, l0);
        split2(zy, h1, l1);
        *(u32*)(zhi + (size_t)node * HH + c2) = (u32)h0 | ((u32)h1 << 16);
        *(u32*)(zlo + (size_t)node * HH + c2) = (u32)l0 | ((u32)l1 << 16);
    }
}

// ---------------- bnrelu: per-block BN finalize; bf16 hb (+f32 h if WF) -----
template <bool WF>
__global__ void k_bnrelu(const float* __restrict__ t, const float* __restrict__ stats,
                         const float* __restrict__ g, const float* __restrict__ b,
                         float invN, float* __restrict__ h, u16* __restrict__ hb,
                         int total4) {
    int i = blockIdx.x * 256 + threadIdx.x;
    if (i >= total4) return;
    int c4 = (i & 31) << 2;
    float sc[4], sh[4];
#pragma unroll
    for (int j = 0; j < 4; j++) {
        float m = stats[c4 + j] * invN;
        float var = stats[128 + c4 + j] * invN - m * m;
        float s = g[c4 + j] * rsqrtf(var + 1e-5f);
        sc[j] = s;
        sh[j] = b[c4 + j] - m * s;
    }
    float4 v = *(const float4*)(t + (size_t)i * 4);
    float4 o;
    o.x = fmaxf(v.x * sc[0] + sh[0], 0.f);
    o.y = fmaxf(v.y * sc[1] + sh[1], 0.f);
    o.z = fmaxf(v.z * sc[2] + sh[2], 0.f);
    o.w = fmaxf(v.w * sc[3] + sh[3], 0.f);
    if (WF) *(float4*)(h + (size_t)i * 4) = o;
    uint2 p = {(u32)f2bf(o.x) | ((u32)f2bf(o.y) << 16),
               (u32)f2bf(o.z) | ((u32)f2bf(o.w) << 16)};
    *(uint2*)(hb + (size_t)i * 4) = p;
}

// ---------------- assign ----------------
__global__ __launch_bounds__(256) void k_assign(
    const float* __restrict__ h, const float* __restrict__ gum,
    const float* __restrict__ w1, const float* __restrict__ b1,
    const float* __restrict__ w2, const float* __restrict__ b2,
    float* __restrict__ assign, int N) {
    __shared__ float s_w1[128 * 64];
    __shared__ float s_w2[64 * 8];
    __shared__ float s_h[32][128];
    __shared__ float s_hid[32][64];
    const int t = threadIdx.x;
    const int n0 = blockIdx.x * 32;
    for (int i = t; i < 128 * 64; i += 256) s_w1[i] = w1[i];
    for (int i = t; i < 512; i += 256) s_w2[i] = w2[i];
    for (int i = t; i < 32 * 32; i += 256) {
        int r = i >> 5, c4 = (i & 31) << 2;
        int gn = n0 + r;
        float4 v = {0.f, 0.f, 0.f, 0.f};
        if (gn < N) v = *(const float4*)(h + (size_t)gn * HH + c4);
        *(float4*)(&s_h[r][c4]) = v;
    }
    __syncthreads();
    for (int o = t; o < 32 * 64; o += 256) {
        int nn = o >> 6, j = o & 63;
        float acc = b1[j];
        for (int k = 0; k < 128; k++) acc = fmaf(s_h[nn][k], s_w1[k * 64 + j], acc);
        s_hid[nn][j] = fmaxf(acc, 0.f);
    }
    __syncthreads();
    int nn = t >> 3, kk = t & 7;
    int gn = n0 + nn;
    float a = b2[kk];
    for (int j = 0; j < 64; j++) a = fmaf(s_hid[nn][j], s_w2[j * 8 + kk], a);
    if (gn < N) a += gum[(size_t)gn * 8 + kk];
    float m = a;
    m = fmaxf(m, __shfl_xor(m, 1));
    m = fmaxf(m, __shfl_xor(m, 2));
    m = fmaxf(m, __shfl_xor(m, 4));
    float e = expf(a - m);
    float s = e;
    s += __shfl_xor(s, 1); s += __shfl_xor(s, 2); s += __shfl_xor(s, 4);
    if (gn < N) assign[(size_t)gn * 8 + kk] = e / s;
}

// ---------------- tail ----------------
__device__ __forceinline__ int lowerb(const int* __restrict__ arr, int n, int val) {
    int lo = 0, hi = n;
    while (lo < hi) {
        int mid = (lo + hi) >> 1;
        if (arr[mid] < val) lo = mid + 1;
        else hi = mid;
    }
    return lo;
}

__global__ __launch_bounds__(1024) void k_pool(
    const float* __restrict__ h, const float* __restrict__ assign,
    const int* __restrict__ batch, float* __restrict__ gmean,
    float* __restrict__ num, float* __restrict__ den, int N) {
    __shared__ float4 s_num[4][8][32];
    __shared__ float4 s_gm[4][32];
    __shared__ float s_den[4][8];
    const int g = blockIdx.x;
    const int t = threadIdx.x;
    const int ns = t >> 8;
    const int k = (t >> 5) & 7;
    const int lane = t & 31;
    const int c4 = lane << 2;
    const int start = lowerb(batch, N, g);
    const int end = lowerb(batch, N, g + 1);
    float4 an = {0.f, 0.f, 0.f, 0.f};
    float4 gm = {0.f, 0.f, 0.f, 0.f};
    float ad = 0.f;
    for (int n = start + ns; n < end; n += 4) {
        float a = assign[(size_t)n * 8 + k];
        const float4 hv = *(const float4*)(h + (size_t)n * HH + c4);
        an.x = fmaf(a, hv.x, an.x);
        an.y = fmaf(a, hv.y, an.y);
        an.z = fmaf(a, hv.z, an.z);
        an.w = fmaf(a, hv.w, an.w);
        if (k == 0) { gm.x += hv.x; gm.y += hv.y; gm.z += hv.z; gm.w += hv.w; }
        ad += a;
    }
    s_num[ns][k][lane] = an;
    if (k == 0) s_gm[ns][lane] = gm;
    if (lane == 0) s_den[ns][k] = ad;
    __syncthreads();
    if (t < 256) {
        float4 a0 = s_num[0][k][lane], a1 = s_num[1][k][lane];
        float4 a2 = s_num[2][k][lane], a3 = s_num[3][k][lane];
        float4 o = {a0.x + a1.x + a2.x + a3.x, a0.y + a1.y + a2.y + a3.y,
                    a0.z + a1.z + a2.z + a3.z, a0.w + a1.w + a2.w + a3.w};
        *(float4*)(num + ((size_t)g * 8 + k) * HH + c4) = o;
        if (t < 32) {
            float4 g0 = s_gm[0][lane], g1 = s_gm[1][lane];
            float4 g2 = s_gm[2][lane], g3 = s_gm[3][lane];
            int cnt = end - start;
            float inv = 1.f / (float)(cnt > 0 ? cnt : 1);
            float4 om = {(g0.x + g1.x + g2.x + g3.x) * inv,
                         (g0.y + g1.y + g2.y + g3.y) * inv,
                         (g0.z + g1.z + g2.z + g3.z) * inv,
                         (g0.w + g1.w + g2.w + g3.w) * inv};
            *(float4*)(gmean + (size_t)g * HH + c4) = om;
        }
        if (t < 8) den[(size_t)g * 8 + t] =
            s_den[0][t] + s_den[1][t] + s_den[2][t] + s_den[3][t];
    }
}

__global__ void k_blob(const float* __restrict__ num, const float* __restrict__ den,
                       const float* __restrict__ w, const float* __restrict__ b,
                       const float* __restrict__ lg, const float* __restrict__ lb,
                       float* __restrict__ blobs) {
    const int gk = blockIdx.x;
    const int c = threadIdx.x;  // 128
    __shared__ float srow[128];
    __shared__ float red[4];
    float d = den[gk] + 1e-8f;
    srow[c] = num[(size_t)gk * HH + c] / d;
    __syncthreads();
    float acc = b[c];
    for (int j = 0; j < 128; j++) acc = fmaf(srow[j], w[j * HH + c], acc);
    float y = fmaxf(acc, 0.f);
    float s = y, q = y * y;
    for (int off = 32; off > 0; off >>= 1) {
        s += __shfl_down(s, off);
        q += __shfl_down(q, off);
    }
    if ((c & 63) == 0) { red[(c >> 6) * 2] = s; red[(c >> 6) * 2 + 1] = q; }
    __syncthreads();
    float S = red[0] + red[2], Q = red[1] + red[3];
    float m = S * (1.f / 128.f);
    float var = Q * (1.f / 128.f) - m * m;
    blobs[(size_t)gk * HH + c] = (y - m) * rsqrtf(var + 1e-5f) * lg[c] + lb[c];
}

__global__ void k_clf1(const float* __restrict__ gmean, const float* __restrict__ blobs,
                       const float* __restrict__ w, const float* __restrict__ bias,
                       float* __restrict__ t4, float* __restrict__ stats) {
    int g = blockIdx.x;
    int c = threadIdx.x;  // 128
    __shared__ float s[256];
    float m = blobs[((size_t)g * 8) * HH + c];
#pragma unroll
    for (int k = 1; k < 8; k++) m = fmaxf(m, blobs[((size_t)g * 8 + k) * HH + c]);
    s[c] = gmean[(size_t)g * HH + c];
    s[128 + c] = m;
    __syncthreads();
    float acc = bias[c];
    for (int j = 0; j < 256; j++) acc = fmaf(s[j], w[j * HH + c], acc);
    t4[(size_t)g * HH + c] = acc;
    atomAddF(&stats[c], acc);
    atomAddF(&stats[HH + c], acc * acc);
}

__global__ void k_clf2(const float* __restrict__ t4, const float* __restrict__ stats,
                       const float* __restrict__ g_, const float* __restrict__ b_,
                       float invG, const float* __restrict__ w,
                       const float* __restrict__ bias, float* __restrict__ out) {
    int g = blockIdx.x;
    int t = threadIdx.x;  // 128
    __shared__ float s[128];
    float m = stats[t] * invG;
    float var = stats[128 + t] * invG - m * m;
    float sc = g_[t] * rsqrtf(var + 1e-5f);
    float sh = b_[t] - m * sc;
    s[t] = fmaxf(t4[(size_t)g * HH + t] * sc + sh, 0.f);
    __syncthreads();
    if (t < 10) {
        float acc = bias[t];
        for (int j = 0; j < 128; j++) acc = fmaf(s[j], w[j * 10 + t], acc);
        out[(size_t)g * 10 + t] = acc;
    }
}

extern "C" void kernel_launch(void* const* d_in, const int* in_sizes, int n_in,
                              void* d_out, int out_size, void* d_ws, size_t ws_size,
                              hipStream_t stream) {
    const float* x      = (const float*)d_in[0];
    const int*   ei     = (const int*)d_in[1];
    const int*   batch  = (const int*)d_in[2];
    const float* gumbel = (const float*)d_in[3];
    const float* inp_w  = (const float*)d_in[4];
    const float* inp_b  = (const float*)d_in[5];
    const float* elin_w = (const float*)d_in[6];
    const float* elin_b = (const float*)d_in[7];
    const float* mlp1_w = (const float*)d_in[8];
    const float* mlp1_b = (const float*)d_in[9];
    const float* mlpbn_g = (const float*)d_in[10];
    const float* mlpbn_b = (const float*)d_in[11];
    const float* mlp2_w = (const float*)d_in[12];
    const float* mlp2_b = (const float*)d_in[13];
    const float* bn_g   = (const float*)d_in[14];
    const float* bn_b   = (const float*)d_in[15];
    const float* bh1_w  = (const float*)d_in[16];
    const float* bh1_b  = (const float*)d_in[17];
    const float* bh2_w  = (const float*)d_in[18];
    const float* bh2_b  = (const float*)d_in[19];
    const float* bm_w   = (const float*)d_in[20];
    const float* bm_b   = (const float*)d_in[21];
    const float* ln_g   = (const float*)d_in[22];
    const float* ln_b   = (const float*)d_in[23];
    const float* clf1_w = (const float*)d_in[24];
    const float* clf1_b = (const float*)d_in[25];
    const float* clfbn_g = (const float*)d_in[26];
    const float* clfbn_b = (const float*)d_in[27];
    const float* clf2_w = (const float*)d_in[28];
    const float* clf2_b = (const float*)d_in[29];
    float* out = (float*)d_out;

    const int N = in_sizes[0] / 64;
    const int E = in_sizes[1] / 2;
    const int G = out_size / 10;

    float* ws = (float*)d_ws;
    float* h      = ws;                                  // N*128
    float* zbuf   = h + (size_t)N * HH;                  // N*128 f32 (multi-use)
    float* t1     = zbuf + (size_t)N * HH;               // N*128
    float* assign = t1 + (size_t)N * HH;                 // N*8
    float* gmean  = assign + (size_t)N * 8;              // G*128
    float* num    = gmean + (size_t)G * HH;              // G*8*128
    float* den    = num + (size_t)G * 8 * HH;            // G*8
    float* blobs  = den + (size_t)G * 8;                 // G*8*128
    float* t4     = blobs + (size_t)G * 8 * HH;          // G*128
    float* statsA = t4 + (size_t)G * HH;                 // 7*256 stats buffers
    u16* Whi = (u16*)(statsA + 7 * 256);                 // WTOT
    u16* Wlo = Whi + WTOT;                               // WTOT
    int* rowptr = (int*)(Wlo + WTOT);                    // N+1
    int* cursor = rowptr + (N + 1);                      // N (also deg)
    int* colidx = cursor + N;                            // E
    int* bsum   = colidx + E;                            // 256
    int* boff   = bsum + 256;                            // 256
    // aliases (disjoint lifetimes):
    u16* hb  = (u16*)t1;          // bf16 h copy; dead once mgemm1 writes t1
    u16* zhi = (u16*)zbuf;        // gather output, dead after mgemm1
    u16* zlo = zhi + (size_t)N * HH;
    float* t2 = zbuf;             // mgemm2 output, dead after bnrelu

    const dim3 B256(256), B128(128), B512(512), B1024(1024);
    const int ntiles = (N + 127) / 128;
    const int gg = ntiles < 256 ? ntiles : 256;
    const int nch = (N + 255) / 256;
    const int e4 = (E + 4 * 256 - 1) / (4 * 256);
    const float invN = 1.f / (float)N;
    const float invG = 1.f / (float)G;

    // weight prep + CSR build + stats clear
    k_prep<<<7, B256, 0, stream>>>(inp_w, mlp1_w, mlp2_w, Whi, Wlo);
    hipMemsetAsync(cursor, 0, (size_t)N * sizeof(int), stream);
    hipMemsetAsync(statsA, 0, 7 * 256 * sizeof(float), stream);
    k_hist<<<e4, B256, 0, stream>>>(ei, cursor, E);
    k_bsum<<<nch, B256, 0, stream>>>(cursor, bsum, N);
    k_scan1<<<1, B256, 0, stream>>>(bsum, boff, rowptr + N, nch);
    k_scan2<<<nch, B256, 0, stream>>>(cursor, boff, rowptr, cursor, N);
    k_fill<<<e4, B256, 0, stream>>>(ei, cursor, colidx, E);

    // hb = bf16(x @ inp_w + inp_b)  (f32 x read directly; split in staging)
    k_mgemm<64, 0, false, false, true><<<gg, B512, 0, stream>>>(
        x, nullptr, nullptr, Whi, Wlo, inp_b, nullptr, nullptr, nullptr, 0.f,
        nullptr, hb, nullptr, N, ntiles);

    for (int l = 0; l < 3; l++) {
        float* sa = statsA + (size_t)(2 * l) * 256;
        float* sb = statsA + (size_t)(2 * l + 1) * 256;
        k_gather<<<(N + 1) / 2, B256, 0, stream>>>(hb, rowptr, colidx,
                                                   elin_w + l * HH, elin_b + l * HH,
                                                   zhi, zlo, N);
        // t1 = z @ W1 + b1 (stats -> sa)
        k_mgemm<128, 2, true, true, false><<<gg, B512, 0, stream>>>(
            nullptr, zhi, zlo, Whi + 8192 + (size_t)l * 16384,
            Wlo + 8192 + (size_t)l * 16384, mlp1_b + l * HH,
            nullptr, nullptr, nullptr, 0.f, t1, nullptr, sa, N, ntiles);
        // t2 = relu(bn(t1)) @ W2 + b2 (per-block finalize from sa; stats -> sb)
        k_mgemm<128, 1, true, true, false><<<gg, B512, 0, stream>>>(
            t1, nullptr, nullptr, Whi + 8192 + (size_t)(3 + l) * 16384,
            Wlo + 8192 + (size_t)(3 + l) * 16384, mlp2_b + l * HH,
            sa, mlpbn_g + l * HH, mlpbn_b + l * HH, invN, t2, nullptr, sb, N, ntiles);
        // h(b) = relu(bn(t2)); f32 h only needed after the last layer
        if (l < 2)
            k_bnrelu<false><<<(N * 32 + 255) / 256, B256, 0, stream>>>(
                t2, sb, bn_g + l * HH, bn_b + l * HH, invN, nullptr, hb, N * 32);
        else
            k_bnrelu<true><<<(N * 32 + 255) / 256, B256, 0, stream>>>(
                t2, sb, bn_g + l * HH, bn_b + l * HH, invN, h, hb, N * 32);
    }

    k_assign<<<(N + 31) / 32, B256, 0, stream>>>(h, gumbel, bh1_w, bh1_b, bh2_w, bh2_b, assign, N);
    k_pool<<<G, B1024, 0, stream>>>(h, assign, batch, gmean, num, den, N);
    k_blob<<<G * 8, B128, 0, stream>>>(num, den, bm_w, bm_b, ln_g, ln_b, blobs);
    float* sc_ = statsA + 6 * 256;
    k_clf1<<<G, B128, 0, stream>>>(gmean, blobs, clf1_w, clf1_b, t4, sc_);
    k_clf2<<<G, B128, 0, stream>>>(t4, sc_, clfbn_g, clfbn_b, invG, clf2_w, clf2_b, out);
}